// Round 5
// baseline (143.266 us; speedup 1.0000x reference)
//
#include <hip/hip_runtime.h>

#define LOG64f 4.1588830833596715f
#define LOG32f 3.4657359027997265f
#define LOG16f 2.7725887222397810f

// ---------------------------------------------------------------------------
// Pass 1 (tiny): per region row r, precompute ew = exp(baseline) and row sums
// R = sum(ew) for all three tracks. 1 wave per region.
// ---------------------------------------------------------------------------
__global__ __launch_bounds__(64) void build_tables_kernel(
    const float* __restrict__ bw0, const float* __restrict__ bw1, const float* __restrict__ bw2,
    float* __restrict__ ew0, float* __restrict__ ew1, float* __restrict__ ew2,
    float* __restrict__ R0, float* __restrict__ R1, float* __restrict__ R2,
    int nRegions)
{
    const int r = blockIdx.x;
    if (r >= nRegions) return;
    const int t = threadIdx.x;

    float e0 = __expf(bw0[(size_t)r * 64 + t]);
    ew0[(size_t)r * 64 + t] = e0;
    float s = e0;
    #pragma unroll
    for (int off = 32; off; off >>= 1) s += __shfl_xor(s, off);
    if (t == 0) R0[r] = s;

    float e1 = 0.f;
    if (t < 32) { e1 = __expf(bw1[(size_t)r * 32 + t]); ew1[(size_t)r * 32 + t] = e1; }
    s = e1;
    #pragma unroll
    for (int off = 32; off; off >>= 1) s += __shfl_xor(s, off);
    if (t == 0) R1[r] = s;

    float e2 = 0.f;
    if (t < 16) { e2 = __expf(bw2[(size_t)r * 16 + t]); ew2[(size_t)r * 16 + t] = e2; }
    s = e2;
    #pragma unroll
    for (int off = 32; off; off >>= 1) s += __shfl_xor(s, off);
    if (t == 0) R2[r] = s;
}

// ---------------------------------------------------------------------------
// Pass 2: one wave = 16 fragments. Streaming part is a masked sum of ew
// (no transcendentals): M = sum_{bc>1} ew[g,j]. Then
//   denom = R[g] + (exp(dv)-1) * M
//   lp    = (bc[b]>1 ? dv : 0) + bw[g,b] - log(denom) + logS
// u[b] is gathered directly by the fragment-owner lane (fl = lane&15).
// ---------------------------------------------------------------------------
__device__ __forceinline__ float msum4(const int4 c, const float4 e)
{
    float m = 0.f;
    m += (c.x > 1 ? e.x : 0.f);
    m += (c.y > 1 ? e.y : 0.f);
    m += (c.z > 1 ? e.z : 0.f);
    m += (c.w > 1 ? e.w : 0.f);
    return m;
}

__global__ __launch_bounds__(256) void frag_pos_dist_kernel(
    const int* __restrict__ bc0, const int* __restrict__ bc1, const int* __restrict__ bc2,
    const int* __restrict__ gix, const int* __restrict__ bix,
    const int* __restrict__ labels, const int* __restrict__ lci,
    const float* __restrict__ bw0, const float* __restrict__ d0,
    const float* __restrict__ bw1, const float* __restrict__ d1,
    const float* __restrict__ bw2, const float* __restrict__ d2,
    const float* __restrict__ ew0, const float* __restrict__ ew1, const float* __restrict__ ew2,
    const float* __restrict__ R0, const float* __restrict__ R1, const float* __restrict__ R2,
    float* __restrict__ out, int N)
{
    const int lane = threadIdx.x & 63;
    const int wid  = blockIdx.x * (blockDim.x >> 6) + (threadIdx.x >> 6);
    const int base = wid * 16;
    if (base >= N) return;
    const int fl = lane & 15;           // fragment slot this lane owns (dup x4)

    // ---------- per-fragment scalars (owner path) ----------
    int nf = base + fl; if (nf >= N) nf = N - 1;
    const int cell = lci[nf];
    const int lab  = labels[cell];
    const float dva = d0[lab], dvb = d1[lab], dvc = d2[lab];
    const int g0v = gix[3 * nf + 0], g1v = gix[3 * nf + 1], g2v = gix[3 * nf + 2];
    const int b0v = bix[3 * nf + 0], b1v = bix[3 * nf + 1], b2v = bix[3 * nf + 2];

    // owner-lane gathers for u[b] (rows are L1/L2-hot)
    const float u0b = (bc0[(size_t)nf * 64 + b0v] > 1 ? dva : 0.f) + bw0[(size_t)g0v * 64 + b0v];
    const float u1b = (bc1[(size_t)nf * 32 + b1v] > 1 ? dvb : 0.f) + bw1[(size_t)g1v * 32 + b1v];
    const float u2b = (bc2[(size_t)nf * 16 + b2v] > 1 ? dvc : 0.f) + bw2[(size_t)g2v * 16 + b2v];
    const float em0 = __expf(dva) - 1.f;
    const float em1 = __expf(dvb) - 1.f;
    const float em2 = __expf(dvc) - 1.f;
    const float r0v = R0[g0v], r1v = R1[g1v], r2v = R2[g2v];

    // ---------- segment geometry & g broadcasts ----------
    const int s16 = lane >> 4, s8 = lane >> 3, s4 = lane >> 2;
    const int f00 = s16, f01 = 4 + s16, f02 = 8 + s16, f03 = 12 + s16;
    const int f10 = s8,  f11 = 8 + s8;
    const int f20 = s4;

    const int g00 = __shfl(g0v, f00), g01 = __shfl(g0v, f01),
              g02 = __shfl(g0v, f02), g03 = __shfl(g0v, f03);
    const int g10 = __shfl(g1v, f10), g11 = __shfl(g1v, f11);
    const int g20 = __shfl(g2v, f20);

    // ---------- issue ALL streaming loads (contiguous 1KB/wave) ----------
    int n00 = base + f00, n01 = base + f01, n02 = base + f02, n03 = base + f03;
    int n10 = base + f10, n11 = base + f11, n20 = base + f20;
    if (n00 >= N) n00 = N - 1;  if (n01 >= N) n01 = N - 1;
    if (n02 >= N) n02 = N - 1;  if (n03 >= N) n03 = N - 1;
    if (n10 >= N) n10 = N - 1;  if (n11 >= N) n11 = N - 1;
    if (n20 >= N) n20 = N - 1;

    const int sub0 = lane & 15, sub1 = lane & 7, sub2 = lane & 3;

    const int4 c00 = ((const int4*)(bc0 + (size_t)n00 * 64))[sub0];
    const int4 c01 = ((const int4*)(bc0 + (size_t)n01 * 64))[sub0];
    const int4 c02 = ((const int4*)(bc0 + (size_t)n02 * 64))[sub0];
    const int4 c03 = ((const int4*)(bc0 + (size_t)n03 * 64))[sub0];
    const int4 c10 = ((const int4*)(bc1 + (size_t)n10 * 32))[sub1];
    const int4 c11 = ((const int4*)(bc1 + (size_t)n11 * 32))[sub1];
    const int4 c20 = ((const int4*)(bc2 + (size_t)n20 * 16))[sub2];

    const float4 e00 = ((const float4*)(ew0 + (size_t)g00 * 64))[sub0];
    const float4 e01 = ((const float4*)(ew0 + (size_t)g01 * 64))[sub0];
    const float4 e02 = ((const float4*)(ew0 + (size_t)g02 * 64))[sub0];
    const float4 e03 = ((const float4*)(ew0 + (size_t)g03 * 64))[sub0];
    const float4 e10 = ((const float4*)(ew1 + (size_t)g10 * 32))[sub1];
    const float4 e11 = ((const float4*)(ew1 + (size_t)g11 * 32))[sub1];
    const float4 e20 = ((const float4*)(ew2 + (size_t)g20 * 16))[sub2];

    // ---------- masked sums + segmented reductions ----------
    float M00 = msum4(c00, e00), M01 = msum4(c01, e01),
          M02 = msum4(c02, e02), M03 = msum4(c03, e03);
    #pragma unroll
    for (int off = 1; off <= 8; off <<= 1) {
        M00 += __shfl_xor(M00, off); M01 += __shfl_xor(M01, off);
        M02 += __shfl_xor(M02, off); M03 += __shfl_xor(M03, off);
    }
    float M10 = msum4(c10, e10), M11 = msum4(c11, e11);
    #pragma unroll
    for (int off = 1; off <= 4; off <<= 1) {
        M10 += __shfl_xor(M10, off); M11 += __shfl_xor(M11, off);
    }
    float M20 = msum4(c20, e20);
    M20 += __shfl_xor(M20, 1); M20 += __shfl_xor(M20, 2);

    // ---------- scatter M back to owner lane fl ----------
    // track 0: fragment fl handled in iter (fl>>2) by segment (fl&3)
    const int src0 = (fl & 3) << 4;
    const float t00 = __shfl(M00, src0), t01 = __shfl(M01, src0),
                t02 = __shfl(M02, src0), t03 = __shfl(M03, src0);
    const int j0 = fl >> 2;
    const float M0 = j0 == 0 ? t00 : j0 == 1 ? t01 : j0 == 2 ? t02 : t03;
    // track 1: iter (fl>>3), segment (fl&7)
    const int src1 = (fl & 7) << 3;
    const float t10 = __shfl(M10, src1), t11 = __shfl(M11, src1);
    const float M1 = (fl >> 3) == 0 ? t10 : t11;
    // track 2: segment fl
    const float M2 = __shfl(M20, fl << 2);

    // ---------- owner lane finishes ----------
    const float acc =
        (u0b - __logf(r0v + em0 * M0) + LOG64f) +
        (u1b - __logf(r1v + em1 * M1) + LOG32f) +
        (u2b - __logf(r2v + em2 * M2) + LOG16f);

    if (lane < 16) {
        const int n = base + lane;
        if (n < N) out[n] = acc;
    }
}

extern "C" void kernel_launch(void* const* d_in, const int* in_sizes, int n_in,
                              void* d_out, int out_size, void* d_ws, size_t ws_size,
                              hipStream_t stream) {
    const int* bc0    = (const int*)d_in[0];
    const int* bc1    = (const int*)d_in[1];
    const int* bc2    = (const int*)d_in[2];
    const int* gix    = (const int*)d_in[3];
    const int* bixp   = (const int*)d_in[4];
    const int* labels = (const int*)d_in[5];
    const int* lci    = (const int*)d_in[6];
    const float* bw0  = (const float*)d_in[7];
    const float* dv0  = (const float*)d_in[8];
    const float* bw1  = (const float*)d_in[9];
    const float* dv1  = (const float*)d_in[10];
    const float* bw2  = (const float*)d_in[11];
    const float* dv2  = (const float*)d_in[12];
    float* out = (float*)d_out;

    const int N = in_sizes[6];           // local_cell_ix has N elements
    const int nRegions = in_sizes[7] / 64;  // baseline_0 is [nRegions, 64]

    // workspace layout (floats)
    float* ws  = (float*)d_ws;
    float* ew0 = ws;                           // nRegions*64
    float* ew1 = ew0 + (size_t)nRegions * 64;  // nRegions*32
    float* ew2 = ew1 + (size_t)nRegions * 32;  // nRegions*16
    float* R0  = ew2 + (size_t)nRegions * 16;  // nRegions
    float* R1  = R0 + nRegions;
    float* R2  = R1 + nRegions;
    const size_t needBytes = sizeof(float) * ((size_t)nRegions * 115);

    if (ws_size < needBytes) {
        // should not happen; bail to a trivially-correct (slow) config is not
        // available, so just return without work (harness would flag it).
        return;
    }

    build_tables_kernel<<<nRegions, 64, 0, stream>>>(
        bw0, bw1, bw2, ew0, ew1, ew2, R0, R1, R2, nRegions);

    const int threads = 256;
    const int fragsPerBlock = 64;        // 4 waves * 16 fragments
    const int blocks = (N + fragsPerBlock - 1) / fragsPerBlock;

    frag_pos_dist_kernel<<<blocks, threads, 0, stream>>>(
        bc0, bc1, bc2, gix, bixp, labels, lci,
        bw0, dv0, bw1, dv1, bw2, dv2,
        ew0, ew1, ew2, R0, R1, R2, out, N);
}

// Round 6
// 114.024 us; speedup vs baseline: 1.2564x; 1.2564x over previous
//
#include <hip/hip_runtime.h>

#define LOG64f 4.1588830833596715f
#define LOG32f 3.4657359027997265f
#define LOG16f 2.7725887222397810f

// ---------------------------------------------------------------------------
// Pass 1 (tiny): per region row r, ew = exp(baseline), R = sum(ew), all tracks.
// ---------------------------------------------------------------------------
__global__ __launch_bounds__(64) void build_tables_kernel(
    const float* __restrict__ bw0, const float* __restrict__ bw1, const float* __restrict__ bw2,
    float* __restrict__ ew0, float* __restrict__ ew1, float* __restrict__ ew2,
    float* __restrict__ R0, float* __restrict__ R1, float* __restrict__ R2,
    int nRegions)
{
    const int r = blockIdx.x;
    if (r >= nRegions) return;
    const int t = threadIdx.x;

    float e0 = __expf(bw0[(size_t)r * 64 + t]);
    ew0[(size_t)r * 64 + t] = e0;
    float s = e0;
    #pragma unroll
    for (int off = 32; off; off >>= 1) s += __shfl_xor(s, off);
    if (t == 0) R0[r] = s;

    float e1 = 0.f;
    if (t < 32) { e1 = __expf(bw1[(size_t)r * 32 + t]); ew1[(size_t)r * 32 + t] = e1; }
    s = e1;
    #pragma unroll
    for (int off = 32; off; off >>= 1) s += __shfl_xor(s, off);
    if (t == 0) R1[r] = s;

    float e2 = 0.f;
    if (t < 16) { e2 = __expf(bw2[(size_t)r * 16 + t]); ew2[(size_t)r * 16 + t] = e2; }
    s = e2;
    #pragma unroll
    for (int off = 32; off; off >>= 1) s += __shfl_xor(s, off);
    if (t == 0) R2[r] = s;
}

// ---------------------------------------------------------------------------
// Pass 2: one wave = 16 fragments, round-4 geometry (every big-array load is a
// contiguous 1KB wave transaction, each byte touched exactly once).
// Per 4-elem chunk: masked sum M += (bc>1)*ew  (2 VALU/elem, no exp);
// the lane owning selected position b recovers u[b]=(bc[b]>1?dv:0)+log(ew[b])
// in-stream. Owner lane: lp = u[b] - log(R[g] + (e^dv - 1)*M) + logS.
// ---------------------------------------------------------------------------
__device__ __forceinline__ void msum4ub(const int4 c, const float4 e, const float dv,
                                        const int b, const int sub, float& m, float& ub)
{
    m  = (c.x > 1 ? e.x : 0.f);
    m += (c.y > 1 ? e.y : 0.f);
    m += (c.z > 1 ? e.z : 0.f);
    m += (c.w > 1 ? e.w : 0.f);
    ub = 0.f;
    if (sub == (b >> 2)) {
        const int r = b & 3;
        const float er = r == 0 ? e.x : r == 1 ? e.y : r == 2 ? e.z : e.w;
        const int   cr = r == 0 ? c.x : r == 1 ? c.y : r == 2 ? c.z : c.w;
        ub = (cr > 1 ? dv : 0.f) + __logf(er);
    }
}

__global__ __launch_bounds__(256) void frag_pos_dist_kernel(
    const int* __restrict__ bc0, const int* __restrict__ bc1, const int* __restrict__ bc2,
    const int* __restrict__ gix, const int* __restrict__ bix,
    const int* __restrict__ labels, const int* __restrict__ lci,
    const float* __restrict__ d0, const float* __restrict__ d1, const float* __restrict__ d2,
    const float* __restrict__ ew0, const float* __restrict__ ew1, const float* __restrict__ ew2,
    const float* __restrict__ R0, const float* __restrict__ R1, const float* __restrict__ R2,
    float* __restrict__ out, int N)
{
    const int lane = threadIdx.x & 63;
    const int wid  = blockIdx.x * (blockDim.x >> 6) + (threadIdx.x >> 6);
    const int base = wid * 16;
    if (base >= N) return;
    const int fl = lane & 15;           // fragment slot this lane owns (dup x4)

    // ---------- per-fragment scalars (owner path) ----------
    int nf = base + fl; if (nf >= N) nf = N - 1;
    const int cell = lci[nf];
    const int lab  = labels[cell];
    const float dva = d0[lab], dvb = d1[lab], dvc = d2[lab];
    const int g0v = gix[3 * nf + 0], g1v = gix[3 * nf + 1], g2v = gix[3 * nf + 2];
    const int b0v = bix[3 * nf + 0], b1v = bix[3 * nf + 1], b2v = bix[3 * nf + 2];

    const float em0 = __expf(dva) - 1.f;
    const float em1 = __expf(dvb) - 1.f;
    const float em2 = __expf(dvc) - 1.f;
    const float r0v = R0[g0v], r1v = R1[g1v], r2v = R2[g2v];

    // ---------- segment geometry & broadcasts ----------
    const int s16 = lane >> 4, s8 = lane >> 3, s4 = lane >> 2;
    const int f00 = s16, f01 = 4 + s16, f02 = 8 + s16, f03 = 12 + s16;
    const int f10 = s8,  f11 = 8 + s8;
    const int f20 = s4;

    const float dv00 = __shfl(dva, f00), dv01 = __shfl(dva, f01),
                dv02 = __shfl(dva, f02), dv03 = __shfl(dva, f03);
    const int   g00  = __shfl(g0v, f00), g01  = __shfl(g0v, f01),
                g02  = __shfl(g0v, f02), g03  = __shfl(g0v, f03);
    const int   b00  = __shfl(b0v, f00), b01  = __shfl(b0v, f01),
                b02  = __shfl(b0v, f02), b03  = __shfl(b0v, f03);

    const float dv10 = __shfl(dvb, f10), dv11 = __shfl(dvb, f11);
    const int   g10  = __shfl(g1v, f10), g11  = __shfl(g1v, f11);
    const int   b10  = __shfl(b1v, f10), b11  = __shfl(b1v, f11);

    const float dv20 = __shfl(dvc, f20);
    const int   g20  = __shfl(g2v, f20);
    const int   b20  = __shfl(b2v, f20);

    // ---------- issue ALL streaming loads (contiguous 1KB/wave) ----------
    int n00 = base + f00, n01 = base + f01, n02 = base + f02, n03 = base + f03;
    int n10 = base + f10, n11 = base + f11, n20 = base + f20;
    if (n00 >= N) n00 = N - 1;  if (n01 >= N) n01 = N - 1;
    if (n02 >= N) n02 = N - 1;  if (n03 >= N) n03 = N - 1;
    if (n10 >= N) n10 = N - 1;  if (n11 >= N) n11 = N - 1;
    if (n20 >= N) n20 = N - 1;

    const int sub0 = lane & 15, sub1 = lane & 7, sub2 = lane & 3;

    const int4 c00 = ((const int4*)(bc0 + (size_t)n00 * 64))[sub0];
    const int4 c01 = ((const int4*)(bc0 + (size_t)n01 * 64))[sub0];
    const int4 c02 = ((const int4*)(bc0 + (size_t)n02 * 64))[sub0];
    const int4 c03 = ((const int4*)(bc0 + (size_t)n03 * 64))[sub0];
    const int4 c10 = ((const int4*)(bc1 + (size_t)n10 * 32))[sub1];
    const int4 c11 = ((const int4*)(bc1 + (size_t)n11 * 32))[sub1];
    const int4 c20 = ((const int4*)(bc2 + (size_t)n20 * 16))[sub2];

    const float4 e00 = ((const float4*)(ew0 + (size_t)g00 * 64))[sub0];
    const float4 e01 = ((const float4*)(ew0 + (size_t)g01 * 64))[sub0];
    const float4 e02 = ((const float4*)(ew0 + (size_t)g02 * 64))[sub0];
    const float4 e03 = ((const float4*)(ew0 + (size_t)g03 * 64))[sub0];
    const float4 e10 = ((const float4*)(ew1 + (size_t)g10 * 32))[sub1];
    const float4 e11 = ((const float4*)(ew1 + (size_t)g11 * 32))[sub1];
    const float4 e20 = ((const float4*)(ew2 + (size_t)g20 * 16))[sub2];

    // ---------- masked sums + in-stream u[b] + segmented reductions ----------
    float M00, M01, M02, M03, U00, U01, U02, U03;
    msum4ub(c00, e00, dv00, b00, sub0, M00, U00);
    msum4ub(c01, e01, dv01, b01, sub0, M01, U01);
    msum4ub(c02, e02, dv02, b02, sub0, M02, U02);
    msum4ub(c03, e03, dv03, b03, sub0, M03, U03);
    #pragma unroll
    for (int off = 1; off <= 8; off <<= 1) {
        M00 += __shfl_xor(M00, off); U00 += __shfl_xor(U00, off);
        M01 += __shfl_xor(M01, off); U01 += __shfl_xor(U01, off);
        M02 += __shfl_xor(M02, off); U02 += __shfl_xor(U02, off);
        M03 += __shfl_xor(M03, off); U03 += __shfl_xor(U03, off);
    }
    float M10, M11, U10, U11;
    msum4ub(c10, e10, dv10, b10, sub1, M10, U10);
    msum4ub(c11, e11, dv11, b11, sub1, M11, U11);
    #pragma unroll
    for (int off = 1; off <= 4; off <<= 1) {
        M10 += __shfl_xor(M10, off); U10 += __shfl_xor(U10, off);
        M11 += __shfl_xor(M11, off); U11 += __shfl_xor(U11, off);
    }
    float M20, U20;
    msum4ub(c20, e20, dv20, b20, sub2, M20, U20);
    M20 += __shfl_xor(M20, 1); U20 += __shfl_xor(U20, 1);
    M20 += __shfl_xor(M20, 2); U20 += __shfl_xor(U20, 2);

    // ---------- scatter M,U back to owner lane fl ----------
    const int src0 = (fl & 3) << 4;
    const float m00 = __shfl(M00, src0), m01 = __shfl(M01, src0),
                m02 = __shfl(M02, src0), m03 = __shfl(M03, src0);
    const float v00 = __shfl(U00, src0), v01 = __shfl(U01, src0),
                v02 = __shfl(U02, src0), v03 = __shfl(U03, src0);
    const int j0 = fl >> 2;
    const float M0 = j0 == 0 ? m00 : j0 == 1 ? m01 : j0 == 2 ? m02 : m03;
    const float U0 = j0 == 0 ? v00 : j0 == 1 ? v01 : j0 == 2 ? v02 : v03;

    const int src1 = (fl & 7) << 3;
    const float m10 = __shfl(M10, src1), m11 = __shfl(M11, src1);
    const float v10 = __shfl(U10, src1), v11 = __shfl(U11, src1);
    const float M1 = (fl >> 3) == 0 ? m10 : m11;
    const float U1 = (fl >> 3) == 0 ? v10 : v11;

    const float M2 = __shfl(M20, fl << 2);
    const float U2 = __shfl(U20, fl << 2);

    // ---------- owner lane finishes ----------
    const float acc =
        (U0 - __logf(r0v + em0 * M0) + LOG64f) +
        (U1 - __logf(r1v + em1 * M1) + LOG32f) +
        (U2 - __logf(r2v + em2 * M2) + LOG16f);

    if (lane < 16) {
        const int n = base + lane;
        if (n < N) out[n] = acc;
    }
}

extern "C" void kernel_launch(void* const* d_in, const int* in_sizes, int n_in,
                              void* d_out, int out_size, void* d_ws, size_t ws_size,
                              hipStream_t stream) {
    const int* bc0    = (const int*)d_in[0];
    const int* bc1    = (const int*)d_in[1];
    const int* bc2    = (const int*)d_in[2];
    const int* gix    = (const int*)d_in[3];
    const int* bixp   = (const int*)d_in[4];
    const int* labels = (const int*)d_in[5];
    const int* lci    = (const int*)d_in[6];
    const float* bw0  = (const float*)d_in[7];
    const float* dv0  = (const float*)d_in[8];
    const float* bw1  = (const float*)d_in[9];
    const float* dv1  = (const float*)d_in[10];
    const float* bw2  = (const float*)d_in[11];
    const float* dv2  = (const float*)d_in[12];
    float* out = (float*)d_out;

    const int N = in_sizes[6];              // local_cell_ix has N elements
    const int nRegions = in_sizes[7] / 64;  // baseline_0 is [nRegions, 64]

    // workspace layout (floats)
    float* ws  = (float*)d_ws;
    float* ew0 = ws;                           // nRegions*64
    float* ew1 = ew0 + (size_t)nRegions * 64;  // nRegions*32
    float* ew2 = ew1 + (size_t)nRegions * 32;  // nRegions*16
    float* R0  = ew2 + (size_t)nRegions * 16;  // nRegions
    float* R1  = R0 + nRegions;
    float* R2  = R1 + nRegions;
    const size_t needBytes = sizeof(float) * ((size_t)nRegions * 115);
    if (ws_size < needBytes) return;

    build_tables_kernel<<<nRegions, 64, 0, stream>>>(
        bw0, bw1, bw2, ew0, ew1, ew2, R0, R1, R2, nRegions);

    const int threads = 256;
    const int fragsPerBlock = 64;        // 4 waves * 16 fragments
    const int blocks = (N + fragsPerBlock - 1) / fragsPerBlock;

    frag_pos_dist_kernel<<<blocks, threads, 0, stream>>>(
        bc0, bc1, bc2, gix, bixp, labels, lci,
        dv0, dv1, dv2,
        ew0, ew1, ew2, R0, R1, R2, out, N);
}

// Round 7
// 104.080 us; speedup vs baseline: 1.3765x; 1.0955x over previous
//
#include <hip/hip_runtime.h>

#define LOG64f 4.1588830833596715f
#define LOG32f 3.4657359027997265f
#define LOG16f 2.7725887222397810f

// One wave = 32 consecutive fragments, processed as two 16-fragment chunks.
// All 14 bc loads (both chunks) issue before the scalar/index dependency
// chain; chunk-B bw loads overlap chunk-A compute. Every big-array load is a
// contiguous 1KB wave transaction, each byte touched exactly once.
// u[b] is fetched directly from its holder lane (owner knows b) -- no U
// reduction chains. M = sum(exp(u)) uses segmented xor reductions.

__device__ __forceinline__ void expsum4(const int4 c, const float4 w, const float dv,
                                        const int b, const int sub, float& s, float& ub)
{
    const float u0 = (c.x > 1 ? dv : 0.f) + w.x;
    const float u1 = (c.y > 1 ? dv : 0.f) + w.y;
    const float u2 = (c.z > 1 ? dv : 0.f) + w.z;
    const float u3 = (c.w > 1 ? dv : 0.f) + w.w;
    s  = (__expf(u0) + __expf(u1)) + (__expf(u2) + __expf(u3));
    ub = 0.f;
    if (sub == (b >> 2)) {
        const int r = b & 3;
        ub = r == 0 ? u0 : r == 1 ? u1 : r == 2 ? u2 : u3;
    }
}

// Process one 16-fragment chunk. Scalars (dva..b2v) are the OWNER-lane values
// for fragment chunkbase + (lane&15). bc rows already loaded by caller.
__device__ __forceinline__ float chunk16(
    const int lane,
    const int4 c00, const int4 c01, const int4 c02, const int4 c03,
    const int4 c10, const int4 c11, const int4 c20,
    const float dva, const float dvb, const float dvc,
    const int g0v, const int g1v, const int g2v,
    const int b0v, const int b1v, const int b2v,
    const float* __restrict__ bw0, const float* __restrict__ bw1,
    const float* __restrict__ bw2)
{
    const int fl = lane & 15;
    const int s16 = lane >> 4, s8 = lane >> 3, s4 = lane >> 2;
    const int f00 = s16, f01 = 4 + s16, f02 = 8 + s16, f03 = 12 + s16;
    const int f10 = s8,  f11 = 8 + s8;
    const int f20 = s4;
    const int sub0 = lane & 15, sub1 = lane & 7, sub2 = lane & 3;

    // ---- broadcasts (segment gets its fragment's scalars) ----
    const float dv00 = __shfl(dva, f00), dv01 = __shfl(dva, f01),
                dv02 = __shfl(dva, f02), dv03 = __shfl(dva, f03);
    const int   g00  = __shfl(g0v, f00), g01  = __shfl(g0v, f01),
                g02  = __shfl(g0v, f02), g03  = __shfl(g0v, f03);
    const int   b00  = __shfl(b0v, f00), b01  = __shfl(b0v, f01),
                b02  = __shfl(b0v, f02), b03  = __shfl(b0v, f03);
    const float dv10 = __shfl(dvb, f10), dv11 = __shfl(dvb, f11);
    const int   g10  = __shfl(g1v, f10), g11  = __shfl(g1v, f11);
    const int   b10  = __shfl(b1v, f10), b11  = __shfl(b1v, f11);
    const float dv20 = __shfl(dvc, f20);
    const int   g20  = __shfl(g2v, f20);
    const int   b20  = __shfl(b2v, f20);

    // ---- baseline row loads (contiguous 1KB/wave) ----
    const float4 w00 = ((const float4*)(bw0 + (size_t)g00 * 64))[sub0];
    const float4 w01 = ((const float4*)(bw0 + (size_t)g01 * 64))[sub0];
    const float4 w02 = ((const float4*)(bw0 + (size_t)g02 * 64))[sub0];
    const float4 w03 = ((const float4*)(bw0 + (size_t)g03 * 64))[sub0];
    const float4 w10 = ((const float4*)(bw1 + (size_t)g10 * 32))[sub1];
    const float4 w11 = ((const float4*)(bw1 + (size_t)g11 * 32))[sub1];
    const float4 w20 = ((const float4*)(bw2 + (size_t)g20 * 16))[sub2];

    // ---- per-chunk exp-sums + holder u[b] ----
    float s00, u00, s01, u01, s02, u02, s03, u03;
    expsum4(c00, w00, dv00, b00, sub0, s00, u00);
    expsum4(c01, w01, dv01, b01, sub0, s01, u01);
    expsum4(c02, w02, dv02, b02, sub0, s02, u02);
    expsum4(c03, w03, dv03, b03, sub0, s03, u03);
    #pragma unroll
    for (int off = 1; off <= 8; off <<= 1) {
        s00 += __shfl_xor(s00, off); s01 += __shfl_xor(s01, off);
        s02 += __shfl_xor(s02, off); s03 += __shfl_xor(s03, off);
    }
    float s10, u10, s11, u11;
    expsum4(c10, w10, dv10, b10, sub1, s10, u10);
    expsum4(c11, w11, dv11, b11, sub1, s11, u11);
    #pragma unroll
    for (int off = 1; off <= 4; off <<= 1) {
        s10 += __shfl_xor(s10, off); s11 += __shfl_xor(s11, off);
    }
    float s20, u20;
    expsum4(c20, w20, dv20, b20, sub2, s20, u20);
    s20 += __shfl_xor(s20, 1); s20 += __shfl_xor(s20, 2);

    // ---- gather S (segment sums) and U (direct from holder lane) ----
    // track 0: frag fl handled in iter j0=fl>>2 by segment fl&3
    const int  src0 = (fl & 3) << 4;
    const float m00 = __shfl(s00, src0), m01 = __shfl(s01, src0),
                m02 = __shfl(s02, src0), m03 = __shfl(s03, src0);
    const int j0 = fl >> 2;
    const float S0 = j0 == 0 ? m00 : j0 == 1 ? m01 : j0 == 2 ? m02 : m03;
    const int  h0 = src0 + (b0v >> 2);
    const float x00 = __shfl(u00, h0), x01 = __shfl(u01, h0),
                x02 = __shfl(u02, h0), x03 = __shfl(u03, h0);
    const float U0 = j0 == 0 ? x00 : j0 == 1 ? x01 : j0 == 2 ? x02 : x03;

    // track 1: iter fl>>3, segment fl&7
    const int  src1 = (fl & 7) << 3;
    const float m10 = __shfl(s10, src1), m11 = __shfl(s11, src1);
    const float S1 = (fl >> 3) == 0 ? m10 : m11;
    const int  h1 = src1 + (b1v >> 2);
    const float x10 = __shfl(u10, h1), x11 = __shfl(u11, h1);
    const float U1 = (fl >> 3) == 0 ? x10 : x11;

    // track 2: segment fl
    const float S2 = __shfl(s20, fl << 2);
    const float U2 = __shfl(u20, (fl << 2) + (b2v >> 2));

    return (U0 - __logf(S0) + LOG64f) +
           (U1 - __logf(S1) + LOG32f) +
           (U2 - __logf(S2) + LOG16f);
}

__global__ __launch_bounds__(256) void frag_pos_dist_kernel(
    const int* __restrict__ bc0, const int* __restrict__ bc1, const int* __restrict__ bc2,
    const int* __restrict__ gix, const int* __restrict__ bix,
    const int* __restrict__ labels, const int* __restrict__ lci,
    const float* __restrict__ bw0, const float* __restrict__ d0,
    const float* __restrict__ bw1, const float* __restrict__ d1,
    const float* __restrict__ bw2, const float* __restrict__ d2,
    float* __restrict__ out, int N)
{
    const int lane = threadIdx.x & 63;
    const int wid  = blockIdx.x * (blockDim.x >> 6) + (threadIdx.x >> 6);
    const int base = wid * 32;
    if (base >= N) return;
    const int fl = lane & 15;
    const int s16 = lane >> 4, s8 = lane >> 3, s4 = lane >> 2;
    const int sub0 = lane & 15, sub1 = lane & 7, sub2 = lane & 3;
    const int NM1 = N - 1;

    // ---------- phase 0: ALL bc loads, both chunks (no dependencies) ----------
    const int nA00 = min(base +      s16, NM1), nA01 = min(base +  4 + s16, NM1),
              nA02 = min(base +  8 + s16, NM1), nA03 = min(base + 12 + s16, NM1);
    const int nA10 = min(base +       s8, NM1), nA11 = min(base +  8 +  s8, NM1);
    const int nA20 = min(base +       s4, NM1);
    const int nB00 = min(base + 16 + s16, NM1), nB01 = min(base + 20 + s16, NM1),
              nB02 = min(base + 24 + s16, NM1), nB03 = min(base + 28 + s16, NM1);
    const int nB10 = min(base + 16 +  s8, NM1), nB11 = min(base + 24 +  s8, NM1);
    const int nB20 = min(base + 16 +  s4, NM1);

    const int4 cA00 = ((const int4*)(bc0 + (size_t)nA00 * 64))[sub0];
    const int4 cA01 = ((const int4*)(bc0 + (size_t)nA01 * 64))[sub0];
    const int4 cA02 = ((const int4*)(bc0 + (size_t)nA02 * 64))[sub0];
    const int4 cA03 = ((const int4*)(bc0 + (size_t)nA03 * 64))[sub0];
    const int4 cA10 = ((const int4*)(bc1 + (size_t)nA10 * 32))[sub1];
    const int4 cA11 = ((const int4*)(bc1 + (size_t)nA11 * 32))[sub1];
    const int4 cA20 = ((const int4*)(bc2 + (size_t)nA20 * 16))[sub2];
    const int4 cB00 = ((const int4*)(bc0 + (size_t)nB00 * 64))[sub0];
    const int4 cB01 = ((const int4*)(bc0 + (size_t)nB01 * 64))[sub0];
    const int4 cB02 = ((const int4*)(bc0 + (size_t)nB02 * 64))[sub0];
    const int4 cB03 = ((const int4*)(bc0 + (size_t)nB03 * 64))[sub0];
    const int4 cB10 = ((const int4*)(bc1 + (size_t)nB10 * 32))[sub1];
    const int4 cB11 = ((const int4*)(bc1 + (size_t)nB11 * 32))[sub1];
    const int4 cB20 = ((const int4*)(bc2 + (size_t)nB20 * 16))[sub2];

    // ---------- phase 1: per-fragment scalars (owner lanes), both chunks ------
    const int nfA = min(base + fl, NM1);
    const int nfB = min(base + 16 + fl, NM1);
    const int cellA = lci[nfA];
    const int cellB = lci[nfB];
    const int labA  = labels[cellA];
    const int labB  = labels[cellB];
    const float dvaA = d0[labA], dvbA = d1[labA], dvcA = d2[labA];
    const float dvaB = d0[labB], dvbB = d1[labB], dvcB = d2[labB];
    const int g0A = gix[3 * nfA + 0], g1A = gix[3 * nfA + 1], g2A = gix[3 * nfA + 2];
    const int g0B = gix[3 * nfB + 0], g1B = gix[3 * nfB + 1], g2B = gix[3 * nfB + 2];
    const int b0A = bix[3 * nfA + 0], b1A = bix[3 * nfA + 1], b2A = bix[3 * nfA + 2];
    const int b0B = bix[3 * nfB + 0], b1B = bix[3 * nfB + 1], b2B = bix[3 * nfB + 2];

    // ---------- phase 2: chunk A, then chunk B (B's bw loads overlap A) -------
    const float accA = chunk16(lane, cA00, cA01, cA02, cA03, cA10, cA11, cA20,
                               dvaA, dvbA, dvcA, g0A, g1A, g2A, b0A, b1A, b2A,
                               bw0, bw1, bw2);
    const float accB = chunk16(lane, cB00, cB01, cB02, cB03, cB10, cB11, cB20,
                               dvaB, dvbB, dvcB, g0B, g1B, g2B, b0B, b1B, b2B,
                               bw0, bw1, bw2);

    // ---------- write: lanes 0..31 own fragments base..base+31 ----------
    if (lane < 32) {
        const int n = base + lane;
        if (n < N) out[n] = (lane < 16) ? accA : accB;
    }
}

extern "C" void kernel_launch(void* const* d_in, const int* in_sizes, int n_in,
                              void* d_out, int out_size, void* d_ws, size_t ws_size,
                              hipStream_t stream) {
    const int* bc0    = (const int*)d_in[0];
    const int* bc1    = (const int*)d_in[1];
    const int* bc2    = (const int*)d_in[2];
    const int* gix    = (const int*)d_in[3];
    const int* bixp   = (const int*)d_in[4];
    const int* labels = (const int*)d_in[5];
    const int* lci    = (const int*)d_in[6];
    const float* bw0  = (const float*)d_in[7];
    const float* dv0  = (const float*)d_in[8];
    const float* bw1  = (const float*)d_in[9];
    const float* dv1  = (const float*)d_in[10];
    const float* bw2  = (const float*)d_in[11];
    const float* dv2  = (const float*)d_in[12];
    float* out = (float*)d_out;

    const int N = in_sizes[6];  // local_cell_ix has N elements
    const int threads = 256;
    const int fragsPerBlock = 128;      // 4 waves * 32 fragments
    const int blocks = (N + fragsPerBlock - 1) / fragsPerBlock;

    frag_pos_dist_kernel<<<blocks, threads, 0, stream>>>(
        bc0, bc1, bc2, gix, bixp, labels, lci,
        bw0, dv0, bw1, dv1, bw2, dv2, out, N);
}